// Round 6
// baseline (542.400 us; speedup 1.0000x reference)
//
#include <hip/hip_runtime.h>
#include <hip/hip_fp16.h>
#include <cstdint>
#include <cstddef>

// DenseCaps dynamic routing, MI355X — R6: MFMA recompute (R5 design) with
// occupancy engineering.
// B=256, R=2048, NC=10, OUT=16, IN=8, 3 routing iters.
//
// R5 post-mortem (280 us): VGPR=256 -> 2 waves/SIMD (occ 9%), 2.29M LDS bank
// conflicts (col*160 stride = bank 0 mod 32), 40 KB LDS. Memory ~7 us/pass,
// VALU-busy ~6.7 us/pass -> latency-bound, not resource-bound.
// R6 changes:
//  - double-MFMA sweep: C[n] computed, consumed for agreement, discarded;
//    recomputed after softmax for the weighted accumulate. Persistent regs
//    ~110 (acc40+vv40+cc10+bf4). __launch_bounds__(256,3).
//  - cross-wave reduction: waves 1-3 stage partials in LDS w/ 164-float
//    padded stride (<=2-way conflicts = free), wave 0 sums + stores P.
//    LDS 31.5 KB.

#define R_   2048
#define NC_  10

typedef _Float16 half8 __attribute__((ext_vector_type(8)));
typedef float   floatx4 __attribute__((ext_vector_type(4)));

__device__ __forceinline__ float rsum16(float x){
  x += __shfl_xor(x, 1, 16);
  x += __shfl_xor(x, 2, 16);
  x += __shfl_xor(x, 4, 16);
  x += __shfl_xor(x, 8, 16);
  return x;
}
// pick element q (0..3) without dynamic register indexing
__device__ __forceinline__ float sel4(float a, float b, float c, float d, int q){
  float x = (q & 1) ? b : a;
  float y = (q & 1) ? d : c;
  return (q & 2) ? y : x;
}

// ---------- pack x -> xh [R][B][8] fp16 ----------
__global__ __launch_bounds__(256) void pack_x_kernel(const float* __restrict__ x,
                                                     _Float16* __restrict__ xh){
  const int r = blockIdx.x, b = threadIdx.x;
  const float4* xp = (const float4*)(x + ((size_t)b * R_ + r) * 8);
  float4 a = xp[0], c = xp[1];
  half8 h;
  h[0]=(_Float16)a.x; h[1]=(_Float16)a.y; h[2]=(_Float16)a.z; h[3]=(_Float16)a.w;
  h[4]=(_Float16)c.x; h[5]=(_Float16)c.y; h[6]=(_Float16)c.z; h[7]=(_Float16)c.w;
  *(half8*)(xh + ((size_t)r * 256 + b) * 8) = h;
}

// ---------- pack W -> wh [R][160][8] fp16  ([r][n*16+o][i]) ----------
__global__ __launch_bounds__(256) void pack_w_kernel(const float* __restrict__ W,
                                                     _Float16* __restrict__ wh){
  const int idx = blockIdx.x * 256 + threadIdx.x;   // r*160 + no
  const int r = idx / 160, no = idx - r * 160;
  half8 h;
  #pragma unroll
  for (int i = 0; i < 8; ++i) h[i] = (_Float16)W[((size_t)r * 8 + i) * 160 + no];
  *(half8*)(wh + (size_t)idx * 8) = h;
}

// ---------- c0 = softmax(b_in) per route ----------
__global__ __launch_bounds__(256) void c0_kernel(const float* __restrict__ b_in,
                                                 float* __restrict__ c0){
  int r = blockIdx.x * 256 + threadIdx.x;
  if (r >= R_) return;
  float t[NC_];
  float m = -1e30f;
  #pragma unroll
  for (int n = 0; n < NC_; ++n){ t[n] = b_in[r * NC_ + n]; m = fmaxf(m, t[n]); }
  float sum = 0.f;
  #pragma unroll
  for (int n = 0; n < NC_; ++n){ t[n] = __expf(t[n] - m); sum += t[n]; }
  float inv = 1.f / sum;
  #pragma unroll
  for (int n = 0; n < NC_; ++n) c0[r * NC_ + n] = t[n] * inv;
}

// ---------- fused MFMA routing pass ----------
// MODE 0: c = c0.  MODE 1: bold = b_in -> bBt.  MODE 2: bold = bBt -> bBt.
// MODE 3: bold = bBt, write c -> c_out ([B][R][10]).
// Grid 1024 = 16 b-tiles x 64 r-chunks; block = 4 waves, wave handles 8 r.
// C/D layout: col(lane&15)=b, row(quad*4+reg)=o (HW-verified m89).
template<int MODE>
__global__ __launch_bounds__(256, 3) void pass_kernel(
    const _Float16* __restrict__ xh,    // [R][256][8]
    const _Float16* __restrict__ wh,    // [R][160][8]
    const float*    __restrict__ c0,    // [R][10]
    const float*    __restrict__ b_in,  // [R][10]
    float*          __restrict__ bBt,   // [R][10][256]
    float*          __restrict__ c_out, // [B][R][10]
    const float*    __restrict__ v,     // [B][160]
    float*          __restrict__ P)     // [64][256][160]
{
  const int bt  = blockIdx.x >> 6;
  const int rcb = blockIdx.x & 63;
  const int wv  = threadIdx.x >> 6;
  const int lane = threadIdx.x & 63;
  const int q   = lane >> 4;
  const int col = lane & 15;
  const int b0  = bt * 16;
  const int b   = b0 + col;

  // v fragment: lane needs v[b][n][o=q*4+j]
  float vv[40];
  if (MODE != 0){
    #pragma unroll
    for (int n = 0; n < 10; ++n){
      float4 t4 = *(const float4*)(v + b * 160 + n * 16 + q * 4);
      vv[4*n] = t4.x; vv[4*n+1] = t4.y; vv[4*n+2] = t4.z; vv[4*n+3] = t4.w;
    }
  }
  float acc[40];
  #pragma unroll
  for (int k = 0; k < 40; ++k) acc[k] = 0.f;

  const half8 hz = {0,0,0,0,0,0,0,0};
  const floatx4 z4 = {0.f, 0.f, 0.f, 0.f};
  const int r0 = rcb * 32 + wv * 8;

  for (int rr = 0; rr < 8; ++rr){
    const int r = r0 + rr;
    half8 bf = hz;
    if (q == 0) bf = *(const half8*)(xh + ((size_t)r * 256 + b) * 8);

    float cc[10];
    if (MODE == 0){
      #pragma unroll
      for (int n = 0; n < 10; ++n) cc[n] = c0[r * 10 + n];   // wave-uniform -> s_load
    } else {
      // sweep 1: agreement logits; C discarded per n
      #pragma unroll
      for (int n = 0; n < 10; ++n){
        half8 af = hz;
        if (q == 0) af = *(const half8*)(wh + ((size_t)r * 160 + n * 16 + col) * 8);
        floatx4 C = __builtin_amdgcn_mfma_f32_16x16x32_f16(af, bf, z4, 0, 0, 0);
        float p = C[0] * vv[4*n];
        p = fmaf(C[1], vv[4*n+1], p);
        p = fmaf(C[2], vv[4*n+2], p);
        p = fmaf(C[3], vv[4*n+3], p);
        p += __shfl_xor(p, 16, 64);
        p += __shfl_xor(p, 32, 64);          // t[b][n] complete in every lane
        float bold = (MODE == 1) ? b_in[r * 10 + n]
                                 : bBt[((size_t)r * 10 + n) * 256 + b];
        cc[n] = bold + p;                    // logits live in cc
      }
      if (MODE != 3){                        // store logits (quad-distributed)
        bBt[((size_t)r * 10 + q)     * 256 + b] = sel4(cc[0], cc[1], cc[2], cc[3], q);
        bBt[((size_t)r * 10 + q + 4) * 256 + b] = sel4(cc[4], cc[5], cc[6], cc[7], q);
        if (q < 2) bBt[((size_t)r * 10 + q + 8) * 256 + b] = (q & 1) ? cc[9] : cc[8];
      }
      float m = cc[0];
      #pragma unroll
      for (int n = 1; n < 10; ++n) m = fmaxf(m, cc[n]);
      float sum = 0.f;
      #pragma unroll
      for (int n = 0; n < 10; ++n){ cc[n] = __expf(cc[n] - m); sum += cc[n]; }
      float inv = 1.f / sum;
      #pragma unroll
      for (int n = 0; n < 10; ++n) cc[n] *= inv;
      if (MODE == 3){                        // store c (quad-distributed)
        const size_t base = ((size_t)b * R_ + r) * 10;
        c_out[base + q]     = sel4(cc[0], cc[1], cc[2], cc[3], q);
        c_out[base + q + 4] = sel4(cc[4], cc[5], cc[6], cc[7], q);
        if (q < 2) c_out[base + q + 8] = (q & 1) ? cc[9] : cc[8];
      }
    }

    // sweep 2: recompute C, weighted accumulate (af reload is L1-hot)
    #pragma unroll
    for (int n = 0; n < 10; ++n){
      half8 af = hz;
      if (q == 0) af = *(const half8*)(wh + ((size_t)r * 160 + n * 16 + col) * 8);
      floatx4 C = __builtin_amdgcn_mfma_f32_16x16x32_f16(af, bf, z4, 0, 0, 0);
      acc[4*n]   = fmaf(cc[n], C[0], acc[4*n]);
      acc[4*n+1] = fmaf(cc[n], C[1], acc[4*n+1]);
      acc[4*n+2] = fmaf(cc[n], C[2], acc[4*n+2]);
      acc[4*n+3] = fmaf(cc[n], C[3], acc[4*n+3]);
    }
  }

  // cross-wave reduction: waves 1-3 stage partials (padded stride 164 ->
  // bank = 4*(col+q) mod 32, <=2-way), wave 0 sums and stores P.
  __shared__ float red[3 * 2624];
  if (wv > 0){
    float* rp = red + (wv - 1) * 2624 + col * 164 + q * 4;
    #pragma unroll
    for (int n = 0; n < 10; ++n){
      rp[n*16+0] = acc[4*n];   rp[n*16+1] = acc[4*n+1];
      rp[n*16+2] = acc[4*n+2]; rp[n*16+3] = acc[4*n+3];
    }
  }
  __syncthreads();
  if (wv == 0){
    const float* rp = red + col * 164 + q * 4;
    float* Pd = P + (((size_t)rcb * 256) + b) * 160 + q * 4;
    #pragma unroll
    for (int n = 0; n < 10; ++n){
      float4 o;
      o.x = acc[4*n]   + rp[n*16]   + rp[2624 + n*16]   + rp[5248 + n*16];
      o.y = acc[4*n+1] + rp[n*16+1] + rp[2624 + n*16+1] + rp[5248 + n*16+1];
      o.z = acc[4*n+2] + rp[n*16+2] + rp[2624 + n*16+2] + rp[5248 + n*16+2];
      o.w = acc[4*n+3] + rp[n*16+3] + rp[2624 + n*16+3] + rp[5248 + n*16+3];
      *(float4*)(Pd + n * 16) = o;
    }
  }
}

// ---------- reduce 64 partials + squash ----------
template<bool FINAL>
__global__ __launch_bounds__(256) void reduce_squash(const float* __restrict__ P,
                                                     float* __restrict__ vout){
  int g = blockIdx.x * 256 + threadIdx.x;   // 0..40959
  float s0 = 0.f, s1 = 0.f;
  #pragma unroll 8
  for (int j = 0; j < 64; j += 2){
    s0 += P[(size_t)j * 40960 + g];
    s1 += P[(size_t)(j + 1) * 40960 + g];
  }
  float s = s0 + s1;
  float ss = rsum16(s * s);
  float f = sqrtf(ss) / (1.f + ss + 1e-8f);
  vout[g] = f * s;
}

extern "C" void kernel_launch(void* const* d_in, const int* in_sizes, int n_in,
                              void* d_out, int out_size, void* d_ws, size_t ws_size,
                              hipStream_t stream){
  const float* x    = (const float*)d_in[0];   // [256,2048,8]
  const float* W    = (const float*)d_in[1];   // [2048,8,160]
  const float* b_in = (const float*)d_in[2];   // [2048,10]
  float* out   = (float*)d_out;
  float* out_v = out;                  // 40960 floats
  float* c_out = out + 40960;          // [B][R][10]

  char* w = (char*)d_ws;
  _Float16* xh = (_Float16*)w;                         // 8,388,608 B
  _Float16* wh = (_Float16*)(w + 8388608);             // 5,242,880 B
  float* bBt   = (float*)(w + 13631488);               // 20,971,520 B
  float* P     = (float*)(w + 34603008);               // 10,485,760 B
  float* v     = (float*)(w + 45088768);               // 163,840 B
  float* c0    = (float*)(w + 45252608);               // 81,920 B

  pack_x_kernel<<<R_, 256, 0, stream>>>(x, xh);
  pack_w_kernel<<<1280, 256, 0, stream>>>(W, wh);
  c0_kernel<<<8, 256, 0, stream>>>(b_in, c0);

  pass_kernel<0><<<1024, 256, 0, stream>>>(xh, wh, c0, b_in, bBt, c_out, v, P);
  reduce_squash<false><<<160, 256, 0, stream>>>(P, v);
  pass_kernel<1><<<1024, 256, 0, stream>>>(xh, wh, c0, b_in, bBt, c_out, v, P);
  reduce_squash<false><<<160, 256, 0, stream>>>(P, v);
  pass_kernel<2><<<1024, 256, 0, stream>>>(xh, wh, c0, b_in, bBt, c_out, v, P);
  reduce_squash<false><<<160, 256, 0, stream>>>(P, v);
  pass_kernel<3><<<1024, 256, 0, stream>>>(xh, wh, c0, b_in, bBt, c_out, v, P);
  reduce_squash<true><<<160, 256, 0, stream>>>(P, out_v);
}

// Round 7
// 459.740 us; speedup vs baseline: 1.1798x; 1.1798x over previous
//
#include <hip/hip_runtime.h>
#include <hip/hip_fp16.h>
#include <cstdint>
#include <cstddef>

// DenseCaps dynamic routing, MI355X — R7: MFMA recompute, live-set shrunk.
// B=256, R=2048, NC=10, OUT=16, IN=8, 3 routing iters.
//
// R5 (280 us): VGPR=256, 2 waves/SIMD, latency-bound, 48 us/pass.
// R6 (542 us): __launch_bounds__(256,3) forced VGPR=84 -> scratch spills
//   (FETCH 12->137 MB, WRITE 30->264 MB). NEVER cap below the live set.
// R7: reduce true pressure instead:
//   - vv[40] -> LDS (stride 164 words, 2-way bank alias = free),
//     re-read per route via ds_read_b128.
//   - double-MFMA sweep kept (C recomputed after softmax, MFMA is cheap).
//   - natural register allocation (~90-110 expected), no min-wave forcing.
//   - LDS: single 31.5 KB buffer shared (barriered) between v-stage and
//     cross-wave reduction -> 5 blocks/CU LDS-wise.

#define R_   2048
#define NC_  10

typedef _Float16 half8 __attribute__((ext_vector_type(8)));
typedef float   floatx4 __attribute__((ext_vector_type(4)));

__device__ __forceinline__ float rsum16(float x){
  x += __shfl_xor(x, 1, 16);
  x += __shfl_xor(x, 2, 16);
  x += __shfl_xor(x, 4, 16);
  x += __shfl_xor(x, 8, 16);
  return x;
}
// pick element q (0..3) without dynamic register indexing
__device__ __forceinline__ float sel4(float a, float b, float c, float d, int q){
  float x = (q & 1) ? b : a;
  float y = (q & 1) ? d : c;
  return (q & 2) ? y : x;
}

// ---------- pack x -> xh [R][B][8] fp16 ----------
__global__ __launch_bounds__(256) void pack_x_kernel(const float* __restrict__ x,
                                                     _Float16* __restrict__ xh){
  const int r = blockIdx.x, b = threadIdx.x;
  const float4* xp = (const float4*)(x + ((size_t)b * R_ + r) * 8);
  float4 a = xp[0], c = xp[1];
  half8 h;
  h[0]=(_Float16)a.x; h[1]=(_Float16)a.y; h[2]=(_Float16)a.z; h[3]=(_Float16)a.w;
  h[4]=(_Float16)c.x; h[5]=(_Float16)c.y; h[6]=(_Float16)c.z; h[7]=(_Float16)c.w;
  *(half8*)(xh + ((size_t)r * 256 + b) * 8) = h;
}

// ---------- pack W -> wh [R][160][8] fp16  ([r][n*16+o][i]) ----------
__global__ __launch_bounds__(256) void pack_w_kernel(const float* __restrict__ W,
                                                     _Float16* __restrict__ wh){
  const int idx = blockIdx.x * 256 + threadIdx.x;   // r*160 + no
  const int r = idx / 160, no = idx - r * 160;
  half8 h;
  #pragma unroll
  for (int i = 0; i < 8; ++i) h[i] = (_Float16)W[((size_t)r * 8 + i) * 160 + no];
  *(half8*)(wh + (size_t)idx * 8) = h;
}

// ---------- c0 = softmax(b_in) per route ----------
__global__ __launch_bounds__(256) void c0_kernel(const float* __restrict__ b_in,
                                                 float* __restrict__ c0){
  int r = blockIdx.x * 256 + threadIdx.x;
  if (r >= R_) return;
  float t[NC_];
  float m = -1e30f;
  #pragma unroll
  for (int n = 0; n < NC_; ++n){ t[n] = b_in[r * NC_ + n]; m = fmaxf(m, t[n]); }
  float sum = 0.f;
  #pragma unroll
  for (int n = 0; n < NC_; ++n){ t[n] = __expf(t[n] - m); sum += t[n]; }
  float inv = 1.f / sum;
  #pragma unroll
  for (int n = 0; n < NC_; ++n) c0[r * NC_ + n] = t[n] * inv;
}

// ---------- fused MFMA routing pass ----------
// MODE 0: c = c0.  MODE 1: bold = b_in -> bBt.  MODE 2: bold = bBt -> bBt.
// MODE 3: bold = bBt, write c -> c_out ([B][R][10]).
// Grid 1024 = 16 b-tiles x 64 r-chunks; block = 4 waves, wave handles 8 r.
// C/D layout: col(lane&15)=b, row(quad*4+reg)=o (HW-verified m89).
template<int MODE>
__global__ __launch_bounds__(256) void pass_kernel(
    const _Float16* __restrict__ xh,    // [R][256][8]
    const _Float16* __restrict__ wh,    // [R][160][8]
    const float*    __restrict__ c0,    // [R][10]
    const float*    __restrict__ b_in,  // [R][10]
    float*          __restrict__ bBt,   // [R][10][256]
    float*          __restrict__ c_out, // [B][R][10]
    const float*    __restrict__ v,     // [B][160]
    float*          __restrict__ P)     // [64][256][160]
{
  const int bt  = blockIdx.x >> 6;
  const int rcb = blockIdx.x & 63;
  const int wv  = threadIdx.x >> 6;
  const int lane = threadIdx.x & 63;
  const int q   = lane >> 4;
  const int col = lane & 15;
  const int b0  = bt * 16;
  const int b   = b0 + col;

  // Shared buffer, time-multiplexed (barrier-separated):
  //  phase 1: smem[0..2623]           = v slice [16 cols][stride 164]
  //  phase 2: smem[(wv-1)*2624 + ...] = cross-wave reduction staging
  __shared__ float smem[3 * 2624];

  if (MODE != 0){
    const float4* vp = (const float4*)(v + b0 * 160);
    for (int i = threadIdx.x; i < 640; i += 256){
      float4 g = vp[i];
      int cl = i / 40, off = i - cl * 40;
      *(float4*)(&smem[cl * 164 + off * 4]) = g;
    }
  }
  __syncthreads();

  float acc[40];
  #pragma unroll
  for (int k = 0; k < 40; ++k) acc[k] = 0.f;

  const half8 hz = {0,0,0,0,0,0,0,0};
  const floatx4 z4 = {0.f, 0.f, 0.f, 0.f};
  const int r0 = rcb * 32 + wv * 8;
  const float* vl = &smem[col * 164 + q * 4];   // vv[n][j] = vl[n*16 + j]

  for (int rr = 0; rr < 8; ++rr){
    const int r = r0 + rr;
    half8 bf = hz;
    if (q == 0) bf = *(const half8*)(xh + ((size_t)r * 256 + b) * 8);

    float cc[10];
    if (MODE == 0){
      #pragma unroll
      for (int n = 0; n < 10; ++n) cc[n] = c0[r * 10 + n];   // wave-uniform -> s_load
    } else {
      // sweep 1: agreement logits; C discarded per n
      #pragma unroll
      for (int n = 0; n < 10; ++n){
        half8 af = hz;
        if (q == 0) af = *(const half8*)(wh + ((size_t)r * 160 + n * 16 + col) * 8);
        floatx4 C = __builtin_amdgcn_mfma_f32_16x16x32_f16(af, bf, z4, 0, 0, 0);
        float4 vf = *(const float4*)(vl + n * 16);
        float p = C[0] * vf.x;
        p = fmaf(C[1], vf.y, p);
        p = fmaf(C[2], vf.z, p);
        p = fmaf(C[3], vf.w, p);
        p += __shfl_xor(p, 16, 64);
        p += __shfl_xor(p, 32, 64);          // t[b][n] complete in every lane
        float bold = (MODE == 1) ? b_in[r * 10 + n]
                                 : bBt[((size_t)r * 10 + n) * 256 + b];
        cc[n] = bold + p;                    // logits live in cc
      }
      if (MODE != 3){                        // store logits (quad-distributed)
        bBt[((size_t)r * 10 + q)     * 256 + b] = sel4(cc[0], cc[1], cc[2], cc[3], q);
        bBt[((size_t)r * 10 + q + 4) * 256 + b] = sel4(cc[4], cc[5], cc[6], cc[7], q);
        if (q < 2) bBt[((size_t)r * 10 + q + 8) * 256 + b] = (q & 1) ? cc[9] : cc[8];
      }
      float m = cc[0];
      #pragma unroll
      for (int n = 1; n < 10; ++n) m = fmaxf(m, cc[n]);
      float sum = 0.f;
      #pragma unroll
      for (int n = 0; n < 10; ++n){ cc[n] = __expf(cc[n] - m); sum += cc[n]; }
      float inv = 1.f / sum;
      #pragma unroll
      for (int n = 0; n < 10; ++n) cc[n] *= inv;
      if (MODE == 3){                        // store c (quad-distributed)
        const size_t base = ((size_t)b * R_ + r) * 10;
        c_out[base + q]     = sel4(cc[0], cc[1], cc[2], cc[3], q);
        c_out[base + q + 4] = sel4(cc[4], cc[5], cc[6], cc[7], q);
        if (q < 2) c_out[base + q + 8] = (q & 1) ? cc[9] : cc[8];
      }
    }

    // sweep 2: recompute C, weighted accumulate (af reload is L1-hot)
    #pragma unroll
    for (int n = 0; n < 10; ++n){
      half8 af = hz;
      if (q == 0) af = *(const half8*)(wh + ((size_t)r * 160 + n * 16 + col) * 8);
      floatx4 C = __builtin_amdgcn_mfma_f32_16x16x32_f16(af, bf, z4, 0, 0, 0);
      acc[4*n]   = fmaf(cc[n], C[0], acc[4*n]);
      acc[4*n+1] = fmaf(cc[n], C[1], acc[4*n+1]);
      acc[4*n+2] = fmaf(cc[n], C[2], acc[4*n+2]);
      acc[4*n+3] = fmaf(cc[n], C[3], acc[4*n+3]);
    }
  }

  // cross-wave reduction (reuses smem; barrier separates from v reads):
  // waves 1-3 stage partials at stride 164 (2-way alias = free), wave 0
  // sums and stores P.
  __syncthreads();
  if (wv > 0){
    float* rp = smem + (wv - 1) * 2624 + col * 164 + q * 4;
    #pragma unroll
    for (int n = 0; n < 10; ++n){
      rp[n*16+0] = acc[4*n];   rp[n*16+1] = acc[4*n+1];
      rp[n*16+2] = acc[4*n+2]; rp[n*16+3] = acc[4*n+3];
    }
  }
  __syncthreads();
  if (wv == 0){
    const float* rp = smem + col * 164 + q * 4;
    float* Pd = P + (((size_t)rcb * 256) + b) * 160 + q * 4;
    #pragma unroll
    for (int n = 0; n < 10; ++n){
      float4 o;
      o.x = acc[4*n]   + rp[n*16]   + rp[2624 + n*16]   + rp[5248 + n*16];
      o.y = acc[4*n+1] + rp[n*16+1] + rp[2624 + n*16+1] + rp[5248 + n*16+1];
      o.z = acc[4*n+2] + rp[n*16+2] + rp[2624 + n*16+2] + rp[5248 + n*16+2];
      o.w = acc[4*n+3] + rp[n*16+3] + rp[2624 + n*16+3] + rp[5248 + n*16+3];
      *(float4*)(Pd + n * 16) = o;
    }
  }
}

// ---------- reduce 64 partials + squash ----------
template<bool FINAL>
__global__ __launch_bounds__(256) void reduce_squash(const float* __restrict__ P,
                                                     float* __restrict__ vout){
  int g = blockIdx.x * 256 + threadIdx.x;   // 0..40959
  float s0 = 0.f, s1 = 0.f;
  #pragma unroll 8
  for (int j = 0; j < 64; j += 2){
    s0 += P[(size_t)j * 40960 + g];
    s1 += P[(size_t)(j + 1) * 40960 + g];
  }
  float s = s0 + s1;
  float ss = rsum16(s * s);
  float f = sqrtf(ss) / (1.f + ss + 1e-8f);
  vout[g] = f * s;
}

extern "C" void kernel_launch(void* const* d_in, const int* in_sizes, int n_in,
                              void* d_out, int out_size, void* d_ws, size_t ws_size,
                              hipStream_t stream){
  const float* x    = (const float*)d_in[0];   // [256,2048,8]
  const float* W    = (const float*)d_in[1];   // [2048,8,160]
  const float* b_in = (const float*)d_in[2];   // [2048,10]
  float* out   = (float*)d_out;
  float* out_v = out;                  // 40960 floats
  float* c_out = out + 40960;          // [B][R][10]

  char* w = (char*)d_ws;
  _Float16* xh = (_Float16*)w;                         // 8,388,608 B
  _Float16* wh = (_Float16*)(w + 8388608);             // 5,242,880 B
  float* bBt   = (float*)(w + 13631488);               // 20,971,520 B
  float* P     = (float*)(w + 34603008);               // 10,485,760 B
  float* v     = (float*)(w + 45088768);               // 163,840 B
  float* c0    = (float*)(w + 45252608);               // 81,920 B

  pack_x_kernel<<<R_, 256, 0, stream>>>(x, xh);
  pack_w_kernel<<<1280, 256, 0, stream>>>(W, wh);
  c0_kernel<<<8, 256, 0, stream>>>(b_in, c0);

  pass_kernel<0><<<1024, 256, 0, stream>>>(xh, wh, c0, b_in, bBt, c_out, v, P);
  reduce_squash<false><<<160, 256, 0, stream>>>(P, v);
  pass_kernel<1><<<1024, 256, 0, stream>>>(xh, wh, c0, b_in, bBt, c_out, v, P);
  reduce_squash<false><<<160, 256, 0, stream>>>(P, v);
  pass_kernel<2><<<1024, 256, 0, stream>>>(xh, wh, c0, b_in, bBt, c_out, v, P);
  reduce_squash<false><<<160, 256, 0, stream>>>(P, v);
  pass_kernel<3><<<1024, 256, 0, stream>>>(xh, wh, c0, b_in, bBt, c_out, v, P);
  reduce_squash<true><<<160, 256, 0, stream>>>(P, out_v);
}